// Round 5
// baseline (171.234 us; speedup 1.0000x reference)
//
#include <hip/hip_runtime.h>
#include <math.h>

#define D      16384
#define D4     4096    // D/4 (float4 per row)
#define S      2048
#define NF     40
#define ROWS   8       // rows of X per block
#define TPB    1024
#define CH4    256     // float4 per chunk
#define CHUNK  1024    // floats per chunk
#define NCHUNK 16

// d_ws layout (float offsets)
#define WW_OFF   0       // WWt[k][j] = w_j . w_k      (1600)
#define UW_OFF   1600    // UWt[k][j] = u_j . w_k      (1600)
#define COEF_OFF 3200    // coef[j]                    (40)
#define UH_OFF   8192    // uhat[k][d]                 (NF*D)
#define WS_FULL  (UH_OFF + NF * D)

__device__ __forceinline__ float dot4(float4 a, float4 b) {
    return fmaf(a.x, b.x, fmaf(a.y, b.y, fmaf(a.z, b.z, a.w * b.w)));
}

__device__ __forceinline__ void fma4(float4& o, float a, float4 u) {
    o.x = fmaf(a, u.x, o.x); o.y = fmaf(a, u.y, o.y);
    o.z = fmaf(a, u.z, o.z); o.w = fmaf(a, u.w, o.w);
}

// ---------------------------------------------------------------------------
// k1: block (k, h): dots WW[k][j], UW[k][j] for j in [5h, 5h+5), own coef_k,
//     and (if doUhat) uhat[k] slice. grid = 320, TPB 512.  (known-good)
// ---------------------------------------------------------------------------
__global__ __launch_bounds__(512) void pair_uhat_kernel(const float* __restrict__ Wg,
                                                        const float* __restrict__ Ug,
                                                        float* __restrict__ tbl,
                                                        int doUhat) {
    const int k = blockIdx.x >> 3;
    const int h = blockIdx.x & 7;
    const int j0 = h * 5;
    const int t = threadIdx.x;
    const int wave = t >> 6, lane = t & 63;

    const float4* W4 = (const float4*)Wg;
    const float4* U4 = (const float4*)Ug;

    float ww[5], wu[5], wkk = 0.f, wku = 0.f;
    #pragma unroll
    for (int j = 0; j < 5; ++j) { ww[j] = 0.f; wu[j] = 0.f; }

    for (int i = 0; i < 8; ++i) {
        const int pos = i * 512 + t;
        float4 wk = W4[(size_t)k * D4 + pos];
        float4 uk = U4[(size_t)k * D4 + pos];
        wkk += dot4(wk, wk);
        wku += dot4(wk, uk);
        #pragma unroll
        for (int j = 0; j < 5; ++j) {
            float4 wj = W4[(size_t)(j0 + j) * D4 + pos];
            float4 uj = U4[(size_t)(j0 + j) * D4 + pos];
            ww[j] += dot4(wk, wj);
            wu[j] += dot4(wk, uj);
        }
    }

    float v[12];
    #pragma unroll
    for (int j = 0; j < 5; ++j) { v[j] = ww[j]; v[5 + j] = wu[j]; }
    v[10] = wkk; v[11] = wku;
    #pragma unroll
    for (int e = 0; e < 12; ++e) {
        #pragma unroll
        for (int off = 32; off >= 1; off >>= 1) v[e] += __shfl_xor(v[e], off);
    }

    __shared__ float red[8][12];
    __shared__ float fin[12];
    __shared__ float coefL;
    if (lane == 0) {
        #pragma unroll
        for (int e = 0; e < 12; ++e) red[wave][e] = v[e];
    }
    __syncthreads();
    if (t < 12) {
        float s = 0.f;
        #pragma unroll
        for (int w = 0; w < 8; ++w) s += red[w][t];
        fin[t] = s;
        if (t < 5)       tbl[WW_OFF + k * NF + j0 + t] = s;
        else if (t < 10) tbl[UW_OFF + k * NF + j0 + (t - 5)] = s;
    }
    __syncthreads();
    if (t == 0) {
        float wwd = fin[10], wud = fin[11];
        float sp = (wud > 0.f) ? (wud + log1pf(expf(-wud))) : log1pf(expf(wud));
        float cf = ((-1.f + sp) - wud) / wwd;
        coefL = cf;
        if (h == 0) tbl[COEF_OFF + k] = cf;
    }
    __syncthreads();

    if (doUhat) {
        const float cf = coefL;
        float4* UH4 = (float4*)(tbl + UH_OFF);
        const int pos = h * 512 + t;
        float4 w = W4[(size_t)k * D4 + pos];
        float4 u = U4[(size_t)k * D4 + pos];
        float4 r;
        r.x = fmaf(cf, w.x, u.x); r.y = fmaf(cf, w.y, u.y);
        r.z = fmaf(cf, w.z, u.z); r.w = fmaf(cf, w.w, u.w);
        UH4[(size_t)k * D4 + pos] = r;
    }
}

// ---------------------------------------------------------------------------
// Main fused kernel (grid 256, TPB 1024, 8 rows/block).
// Register budget is the design constraint: LDS (~73 KB) -> 2 blocks/CU max
// -> compiler targets 8 waves/SIMD -> 64-VGPR cap (R2/R3 measured). So every
// phase is partitioned to keep the live set under ~62 VGPRs:
//   A: wave = (row-team of 4 rows) x (k-team of 5)  -> acc[4][5]+wv[5] ~ 62
//   B: 40-step recurrence, one wave per row
//   C: one float4 column/thread, 4 passes          -> o[8]+uh      ~ 50
// No software pipelining, no launch_bounds min-occupancy, no LDS padding
// (R4's combination of those broke correctness).
// ---------------------------------------------------------------------------
template <bool PRE>
__global__ __launch_bounds__(TPB) void flow_main(const float* __restrict__ Xg,
                                                 const float* __restrict__ Wg,
                                                 const float* __restrict__ Ug,
                                                 const float* __restrict__ Bg,
                                                 const float* __restrict__ tbl,
                                                 float* __restrict__ Og) {
    const int t = threadIdx.x;
    const int wave = t >> 6, lane = t & 63;
    const int rowBase = blockIdx.x * ROWS;

    __shared__ __align__(16) float xs[2][ROWS][CHUNK];   // 64 KB
    __shared__ __align__(16) float gts[NF][NF + 1];
    __shared__ __align__(16) float c0p[NF][ROWS];
    __shared__ __align__(16) float aTs[NF][ROWS];
    __shared__ float bsS[NF];
    __shared__ float coefS[NF];

    const float4* X4 = (const float4*)Xg;
    const float4* W4 = (const float4*)Wg;
    const float4* U4 = (const float4*)Ug;
    const float4* UH4 = (const float4*)(tbl + UH_OFF);

    // prologue: Gt computed into LDS from WW/UW/coef
    for (int e = t; e < NF * NF; e += TPB) {
        const int jj = e % NF;
        gts[e / NF][jj] = tbl[UW_OFF + e] + tbl[COEF_OFF + jj] * tbl[WW_OFF + e];
    }
    if (t < NF) { bsS[t] = Bg[t]; coefS[t] = tbl[COEF_OFF + t]; }

    // staging role: 2 rows x one float4 per thread per chunk
    const int srow = (t >> 8) * 2;
    const int sc4  = t & 255;

    float4 p0 = X4[(size_t)(rowBase + srow)     * D4 + sc4];
    float4 p1 = X4[(size_t)(rowBase + srow + 1) * D4 + sc4];
    *(float4*)&xs[0][srow][sc4 * 4]     = p0;
    *(float4*)&xs[0][srow + 1][sc4 * 4] = p1;
    __syncthreads();

    // ---- Phase A: wave = (rt row-team) x (kt k-team) ----
    const int kt = wave & 7, rt = wave >> 3;
    const int k0 = kt * 5, r0 = rt * 4;

    float acc[4][5];
    #pragma unroll
    for (int r = 0; r < 4; ++r)
        #pragma unroll
        for (int kk = 0; kk < 5; ++kk) acc[r][kk] = 0.f;

    int b = 0;
    for (int c = 0; c < NCHUNK; ++c) {
        if (c + 1 < NCHUNK) {
            p0 = X4[(size_t)(rowBase + srow)     * D4 + (c + 1) * CH4 + sc4];
            p1 = X4[(size_t)(rowBase + srow + 1) * D4 + (c + 1) * CH4 + sc4];
        }
        #pragma unroll 1
        for (int s = 0; s < 4; ++s) {
            const int col4 = c * CH4 + s * 64 + lane;
            float4 wv[5];
            #pragma unroll
            for (int kk = 0; kk < 5; ++kk)
                wv[kk] = W4[(size_t)(k0 + kk) * D4 + col4];
            const int lc = (s * 64 + lane) * 4;
            #pragma unroll
            for (int r = 0; r < 4; ++r) {
                float4 xv = *(const float4*)&xs[b][r0 + r][lc];
                #pragma unroll
                for (int kk = 0; kk < 5; ++kk)
                    acc[r][kk] = fmaf(xv.x, wv[kk].x,
                                 fmaf(xv.y, wv[kk].y,
                                 fmaf(xv.z, wv[kk].z,
                                 fmaf(xv.w, wv[kk].w, acc[r][kk]))));
            }
        }
        if (c + 1 < NCHUNK) {
            *(float4*)&xs[b ^ 1][srow][sc4 * 4]     = p0;
            *(float4*)&xs[b ^ 1][srow + 1][sc4 * 4] = p1;
        }
        __syncthreads();
        b ^= 1;
    }

    // reduce partial dots across the wave, write c0
    #pragma unroll
    for (int r = 0; r < 4; ++r)
        #pragma unroll
        for (int kk = 0; kk < 5; ++kk) {
            float v = acc[r][kk];
            #pragma unroll
            for (int off = 32; off >= 1; off >>= 1) v += __shfl_xor(v, off);
            acc[r][kk] = v;
        }
    if (lane == 0) {
        #pragma unroll
        for (int kk = 0; kk < 5; ++kk)
            #pragma unroll
            for (int r = 0; r < 4; ++r)
                c0p[k0 + kk][r0 + r] = acc[r][kk];
    }
    __syncthreads();

    // ---- issue Phase C p=0 X re-loads now (overlap with Phase B) ----
    float4 o[ROWS];
    {
        const int col = wave * 64 + lane;
        #pragma unroll
        for (int r = 0; r < ROWS; ++r)
            o[r] = X4[(size_t)(rowBase + r) * D4 + col];
    }

    // ---- Phase B: recurrence, one wave per row ----
    if (wave < ROWS) {
        const int r = wave, j = lane;
        float aj = 0.f;
        for (int k = 0; k < NF; ++k) {
            float gv = (j < k) ? gts[k][j] : 0.f;
            float tv = aj * gv;
            #pragma unroll
            for (int off = 32; off >= 1; off >>= 1) tv += __shfl_xor(tv, off);
            float sum = c0p[k][r] + bsS[k] + tv;
            float ak = tanhf(sum);
            if (j == k) aj = ak;
        }
        if (j < NF) aTs[j][r] = aj;
    }
    __syncthreads();

    // ---- Phase C: out = x0 + sum_k a[r][k] * uhat_k ----
    float4* O4 = (float4*)Og;
    #pragma unroll 1
    for (int p = 0; p < 4; ++p) {
        const int col = p * 1024 + wave * 64 + lane;
        if (p > 0) {
            #pragma unroll
            for (int r = 0; r < ROWS; ++r)
                o[r] = X4[(size_t)(rowBase + r) * D4 + col];
        }
        #pragma unroll 2
        for (int k = 0; k < NF; ++k) {
            float4 uh;
            if (PRE) {
                uh = UH4[(size_t)k * D4 + col];
            } else {
                float4 uu = U4[(size_t)k * D4 + col];
                float4 wv = W4[(size_t)k * D4 + col];
                const float cf = coefS[k];
                uh.x = fmaf(cf, wv.x, uu.x);
                uh.y = fmaf(cf, wv.y, uu.y);
                uh.z = fmaf(cf, wv.z, uu.z);
                uh.w = fmaf(cf, wv.w, uu.w);
            }
            float4 alo = *(const float4*)&aTs[k][0];
            float4 ahi = *(const float4*)&aTs[k][4];
            fma4(o[0], alo.x, uh); fma4(o[1], alo.y, uh);
            fma4(o[2], alo.z, uh); fma4(o[3], alo.w, uh);
            fma4(o[4], ahi.x, uh); fma4(o[5], ahi.y, uh);
            fma4(o[6], ahi.z, uh); fma4(o[7], ahi.w, uh);
        }
        #pragma unroll
        for (int r = 0; r < ROWS; ++r)
            O4[(size_t)(rowBase + r) * D4 + col] = o[r];
    }
}

extern "C" void kernel_launch(void* const* d_in, const int* in_sizes, int n_in,
                              void* d_out, int out_size, void* d_ws, size_t ws_size,
                              hipStream_t stream) {
    const float* X  = (const float*)d_in[0];
    const float* Wg = (const float*)d_in[1];
    const float* Ug = (const float*)d_in[2];
    const float* Bg = (const float*)d_in[3];
    float* out = (float*)d_out;
    float* tbl = (float*)d_ws;

    const bool pre = ws_size >= (size_t)WS_FULL * sizeof(float);

    pair_uhat_kernel<<<NF * 8, 512, 0, stream>>>(Wg, Ug, tbl, pre ? 1 : 0);
    if (pre) {
        flow_main<true><<<S / ROWS, TPB, 0, stream>>>(X, Wg, Ug, Bg, tbl, out);
    } else {
        flow_main<false><<<S / ROWS, TPB, 0, stream>>>(X, Wg, Ug, Bg, tbl, out);
    }
}